// Round 15
// baseline (105.165 us; speedup 1.0000x reference)
//
#include <hip/hip_runtime.h>
#include <stdint.h>

// Problem constants (fixed by the reference)
#define B_IMG        64
#define M_GT         100
#define N_PROP       4000
#define K_TOT        4100          // N + M (proposal_append_gt)
#define NUM_CLASSES_ 80
#define BATCH_PER    512
#define NUM_FG_TGT   128
#define OUT_STRIDE   (B_IMG * BATCH_PER)   // 32768 elements per output tensor

// Kernel 1 (match) geometry: 2-lane m-split, 2112 blocks x 256 threads
#define NT1          256
#define BPI1         33                    // blocks per image (33*128 >= 4100)
#define EPB1         128                   // elements per block (2 lanes/elem)
// Kernel 2 (select) geometry
#define NTH          1024
#define HALF_CAP     1024
#define KITER        ((K_TOT + NTH - 1) / NTH)   // 5 uniform trips
#define NTF          1024                  // fallback kernel threads

// Key packing (uint64 compare gives exact (fg, pri, idx) descending order;
// midx rides in the low bits — idx is unique so it never affects ordering):
//   bit 50      : fg flag
//   bits 49..20 : float bits of priority (pri in [0,1) => bits < 2^30)
//   bits 19..7  : element index (0..4099 < 8192)  — reproduces the reversed-
//                 stable-argsort tiebreak (higher idx first on equal pri)
//   bits  6..0  : matched gt index (0..99 < 128)

// IoU, contraction off, branchless: uni > 0 always (box wh >= 8 => areas > 0)
// and inter==0 gives +0.0/uni == +0.0 — bit-identical to the reference's
// where(inter>0, inter/uni, 0). Validated absmax-0 in R12/R13.
// area_a precomputed once per block with the identical expression
// (g.z-g.x)*(g.w-g.y) — same inputs, same op order => same bits.
__device__ __forceinline__ float iou_a(float4 g, float area_a,
                                       float bx1, float by1, float bx2, float by2,
                                       float area_b) {
#pragma clang fp contract(off)
    float ltx = fmaxf(g.x, bx1), lty = fmaxf(g.y, by1);
    float rbx = fminf(g.z, bx2), rby = fminf(g.w, by2);
    float wx = fmaxf(rbx - ltx, 0.0f);
    float wy = fmaxf(rby - lty, 0.0f);
    float inter = wx * wy;
    float uni = area_a + area_b - inter;
    return inter / uni;
}

__device__ __forceinline__ float iou_g(float4 g,
                                       float bx1, float by1, float bx2, float by2,
                                       float area_b) {
#pragma clang fp contract(off)
    float area_a = (g.z - g.x) * (g.w - g.y);
    float ltx = fmaxf(g.x, bx1), lty = fmaxf(g.y, by1);
    float rbx = fminf(g.z, bx2), rby = fminf(g.w, by2);
    float wx = fmaxf(rbx - ltx, 0.0f);
    float wy = fmaxf(rby - lty, 0.0f);
    float inter = wx * wy;
    float uni = area_a + area_b - inter;
    return inter / uni;
}

// area helper with pragma at compound-statement start (fixes R14 compile error)
__device__ __forceinline__ float box_area(float4 g) {
#pragma clang fp contract(off)
    return (g.z - g.x) * (g.w - g.y);
}

// ---------------------------------------------------------------------------
// Kernel 1: IoU argmax + key build. Grid = 64 x 33 blocks x 256 threads.
// 2 lanes per element (lane parity picks m in [0,50) / [50,100)); one
// __shfl_xor combines — upper half wins only on strict > == sequential
// first-occurrence argmax (validated absmax-0 R12/R13). gt areas precomputed
// in LDS (~10% fewer VALU ops per iteration, bit-identical).
// Key stores are AGENT-COHERENT: visibility to kernel 2 does not depend on
// runtime inter-kernel cache maintenance (which graph replay elides — the
// diagnosed cause of R3's replay-only divergence with plain stores).
// ---------------------------------------------------------------------------
__global__ __launch_bounds__(NT1, 8) void match_kernel(
        const float* __restrict__ gt_boxes,    // [B, M, 4]
        const float* __restrict__ prop_boxes,  // [B, N, 4]
        const float* __restrict__ rand_pri,    // [B, K]
        uint64_t*    __restrict__ keys)        // [B, K] ws
{
    __shared__ float4 s_gtb4[M_GT];            // 1.6 KB
    __shared__ float  s_gta[M_GT];             // 0.4 KB

    const int blk = blockIdx.x;
    const int b   = blk / BPI1;                // image
    const int q   = blk % BPI1;                // slice
    const int tid = threadIdx.x;

    for (int i = tid; i < M_GT; i += NT1)
        s_gtb4[i] = ((const float4*)gt_boxes)[(size_t)b * M_GT + i];
    __syncthreads();
    for (int i = tid; i < M_GT; i += NT1)
        s_gta[i] = box_area(s_gtb4[i]);
    __syncthreads();

    const int e    = q * EPB1 + (tid >> 1);    // element id in image
    const int half = tid & 1;                  // 0: m in [0,50), 1: [50,100)
    if (e >= K_TOT) return;                    // contiguous tail exit (pairs together)

    const uint32_t pb = __float_as_uint(rand_pri[(size_t)b * K_TOT + e]);
    float4 bp;
    if (e < N_PROP)
        bp = *(const float4*)(prop_boxes + ((size_t)b * N_PROP + e) * 4);
    else
        bp = s_gtb4[e - N_PROP];
    const float area_b = box_area(bp);
    const int mlo = half * (M_GT / 2);
    float best = -1.0f; int bidx = mlo;
#pragma unroll 2
    for (int m = mlo; m < mlo + M_GT / 2; ++m) {
        float iv = iou_a(s_gtb4[m], s_gta[m], bp.x, bp.y, bp.z, bp.w, area_b);
        if (iv > best) { best = iv; bidx = m; }    // strict > => first max in half
    }
    // combine halves: upper wins only on strict > (== sequential argmax)
    const float ob = __shfl_xor(best, 1);
    const int   oi = __shfl_xor(bidx, 1);
    if (half == 0) {
        if (ob > best) { best = ob; bidx = oi; }
        const bool fg = best >= 0.5f;
        uint64_t key = (fg ? (1ull << 50) : 0ull)
                     | ((uint64_t)pb << 20)
                     | ((uint64_t)e  << 7)
                     | (uint64_t)bidx;
        __hip_atomic_store(&keys[(size_t)b * K_TOT + e], key,
                           __ATOMIC_RELAXED, __HIP_MEMORY_SCOPE_AGENT);
    }
}

// ---------------------------------------------------------------------------
// Kernel 2: exact top-k select + rank + emit. Grid = 64 blocks x 1024 thr.
// Entry acquire fence drops stale cache lines from prior replays (keys were
// written coherently; the graph edge orders execution). Compaction uses
// WAVE-AGGREGATED atomics: ballot + popcount + one LDS atomicAdd per group
// per wave — replaces 4100 serialized same-address LDS RMWs (~13 us) with
// ~160 wave-RMWs. Candidate order changes; ranks are order-independent.
// ---------------------------------------------------------------------------
__global__ __launch_bounds__(NTH) void select_kernel(
        const float* __restrict__ gt_boxes,    // [B, M, 4]
        const float* __restrict__ prop_boxes,  // [B, N, 4]
        const int*   __restrict__ gt_classes,  // [B, M]
        const uint64_t* __restrict__ keys,     // [B, K] ws
        float*       __restrict__ out)         // 5 x [B, 512] flat
{
    __shared__ uint64_t s_keys[K_TOT];         // 32.8 KB
    __shared__ uint64_t s_cand[2 * HALF_CAP];  // 16 KB: fg half | bg half
    __shared__ int      s_hist[2][256];        // 2 KB
    __shared__ float4   s_gtb4[M_GT];
    __shared__ float    s_gta[M_GT];
    __shared__ int      s_gtc[M_GT];
    __shared__ float    s_out[5][BATCH_PER];   // 10 KB staging
    __shared__ int      s_T[2], s_needed[2], s_cnt[2];

    const int b   = blockIdx.x;
    const int tid = threadIdx.x;

    __builtin_amdgcn_fence(__ATOMIC_ACQUIRE, "agent");  // drop stale cache lines

    for (int i = tid; i < 512; i += NTH) s_hist[i >> 8][i & 255] = 0;
    if (tid < 2) s_cnt[tid] = 0;
    for (int i = tid; i < M_GT; i += NTH) {
        s_gtb4[i] = ((const float4*)gt_boxes)[(size_t)b * M_GT + i];
        s_gtc[i]  = gt_classes[(size_t)b * M_GT + i];
    }
    __syncthreads();
    for (int i = tid; i < M_GT; i += NTH)
        s_gta[i] = box_area(s_gtb4[i]);

    // stage keys + histogram per group (uniform trips; guarded body)
#pragma unroll
    for (int kb = 0; kb < KITER; ++kb) {
        int k = kb * NTH + tid;
        if (k < K_TOT) {
            uint64_t key = keys[(size_t)b * K_TOT + k];
            s_keys[k] = key;
            int g = ((key >> 50) & 1ull) ? 0 : 1;   // 0 = fg, 1 = bg
            uint32_t pbits = (uint32_t)((key >> 20) & 0x3FFFFFFFull);
            int bucket = min(255, (int)(__uint_as_float(pbits) * 256.0f));
            atomicAdd(&s_hist[g][bucket], 1);       // 512 distinct buckets: cheap
        }
    }
    __syncthreads();

    // Hillis-Steele suffix scan over each 256-bucket histogram
    for (int d = 1; d < 256; d <<= 1) {
        int v = 0, g = tid >> 8, t = tid & 255;
        bool act = (tid < 512) && (t + d < 256);
        if (act) v = s_hist[g][t + d];
        __syncthreads();
        if (act) s_hist[g][t] += v;
        __syncthreads();
    }

    if (tid == 0) {
        int fg_total = s_hist[0][0];
        int bg_total = s_hist[1][0];
        int nfg = min(NUM_FG_TGT, fg_total);
        int nbg = min(BATCH_PER - nfg, bg_total);
        s_needed[0] = nfg; s_needed[1] = nbg;
    }
    __syncthreads();

    // bucket threshold: max t with S[t] >= need (unique crossing)
    if (tid < 512) {
        int g = tid >> 8, t = tid & 255;
        int need = s_needed[g];
        int St  = s_hist[g][t];
        int St1 = (t == 255) ? -1 : s_hist[g][t + 1];
        if (St >= need && St1 < need) s_T[g] = t;
    }
    if (tid < BATCH_PER) {                     // prefill invalid pattern
        s_out[0][tid] = 0.0f; s_out[1][tid] = -1.0f;
        s_out[2][tid] = -1.0f; s_out[3][tid] = -1.0f;
    }
    __syncthreads();

    const int nfg = s_needed[0], nbg = s_needed[1];
    if (tid < BATCH_PER)
        s_out[4][tid] = (tid < nfg + nbg) ? 1.0f : 0.0f;

    // compaction into disjoint halves — wave-aggregated atomics
    const int lane = tid & 63;
    const uint64_t ltm = (1ull << lane) - 1ull;
#pragma unroll
    for (int kb = 0; kb < KITER; ++kb) {
        int k = kb * NTH + tid;
        bool in = k < K_TOT;
        uint64_t key = in ? s_keys[k] : 0ull;
        bool isfg = in && (((key >> 50) & 1ull) != 0ull);
        bool sel = false;
        if (in) {
            uint32_t pbits = (uint32_t)((key >> 20) & 0x3FFFFFFFull);
            int bucket = min(255, (int)(__uint_as_float(pbits) * 256.0f));
            sel = bucket >= s_T[isfg ? 0 : 1];
        }
        const bool sf = sel && isfg;
        const bool sb = sel && !isfg;
        const uint64_t bf = __ballot(sf);
        const uint64_t bb = __ballot(sb);
        int basef = 0, baseb = 0;
        if (lane == 0) {
            if (bf) basef = atomicAdd(&s_cnt[0], (int)__popcll(bf));
            if (bb) baseb = atomicAdd(&s_cnt[1], (int)__popcll(bb));
        }
        basef = __shfl(basef, 0);
        baseb = __shfl(baseb, 0);
        if (sf) {
            int pos = basef + (int)__popcll(bf & ltm);
            if (pos < HALF_CAP) s_cand[pos] = key;
        }
        if (sb) {
            int pos = baseb + (int)__popcll(bb & ltm);
            if (pos < HALF_CAP) s_cand[HALF_CAP + pos] = key;
        }
    }
    __syncthreads();

    // rank within each half (keys unique -> each slot written exactly once,
    // independent of compaction order) and emit
    const int fgc = min(s_cnt[0], HALF_CAP);
    const int bgc = min(s_cnt[1], HALF_CAP);
    for (int c = tid; c < fgc + bgc; c += NTH) {
        const bool isfg = (c < fgc);
        const int  base = isfg ? 0 : HALF_CAP;
        const int  cnt  = isfg ? fgc : bgc;
        const int  ci   = isfg ? c : (c - fgc);
        const uint64_t kc = s_cand[base + ci];
        int r = 0;
        for (int j = 0; j < cnt; ++j)          // broadcast LDS reads
            r += (s_cand[base + j] > kc) ? 1 : 0;
        int slot = -1;
        if (isfg) { if (r < nfg) slot = r; }
        else      { if (r < nbg) slot = nfg + r; }
        if (slot >= 0) {
            int idx = (int)((kc >> 7) & 0x1FFFull);
            int mi  = (int)(kc & 0x7Full);
            float4 bp;
            if (idx < N_PROP)
                bp = *(const float4*)(prop_boxes + ((size_t)b * N_PROP + idx) * 4);
            else
                bp = s_gtb4[idx - N_PROP];
            const float area_b = box_area(bp);
            // bit-exact matched_vals[idx]: same fp ops on same inputs as K1
            float iou = iou_a(s_gtb4[mi], s_gta[mi], bp.x, bp.y, bp.z, bp.w, area_b);
            s_out[0][slot] = iou;
            s_out[1][slot] = (float)idx;
            s_out[2][slot] = (float)(isfg ? s_gtc[mi] : NUM_CLASSES_);
            s_out[3][slot] = (float)mi;
        }
    }
    __syncthreads();

    // coalesced write-out
    for (int i = tid; i < 5 * BATCH_PER; i += NTH) {
        int o = i / BATCH_PER, p = i % BATCH_PER;
        out[(size_t)o * OUT_STRIDE + (size_t)b * BATCH_PER + p] = s_out[o][p];
    }
}

// ---------------------------------------------------------------------------
// Fallback: proven single kernel (one block per image, zero workspace).
// Used only if ws_size is too small for the key buffer.
// ---------------------------------------------------------------------------
__global__ __launch_bounds__(NTF) void roiheads_fallback(
        const float* __restrict__ gt_boxes,
        const float* __restrict__ prop_boxes,
        const int*   __restrict__ gt_classes,
        const float* __restrict__ rand_pri,
        float*       __restrict__ out)
{
    __shared__ uint64_t s_keys[K_TOT];
    __shared__ uint64_t s_cand[2 * HALF_CAP];
    __shared__ int      s_hist[2][256];
    __shared__ float4   s_gtb4[M_GT];
    __shared__ int      s_gtc[M_GT];
    __shared__ float    s_out[5][BATCH_PER];
    __shared__ int      s_T[2], s_needed[2], s_cnt[2];

    const int b   = blockIdx.x;
    const int tid = threadIdx.x;

    for (int i = tid; i < 512; i += NTF) s_hist[i >> 8][i & 255] = 0;
    if (tid < 2) s_cnt[tid] = 0;
    for (int i = tid; i < M_GT; i += NTF) {
        s_gtb4[i] = ((const float4*)gt_boxes)[(size_t)b * M_GT + i];
        s_gtc[i]  = gt_classes[(size_t)b * M_GT + i];
    }
    __syncthreads();

    for (int k = tid; k < K_TOT; k += NTF) {
        float4 bp;
        if (k < N_PROP)
            bp = *(const float4*)(prop_boxes + ((size_t)b * N_PROP + k) * 4);
        else
            bp = s_gtb4[k - N_PROP];
        const float area_b = box_area(bp);
        float best = -1.0f; int bidx = 0;
        for (int m = 0; m < M_GT; ++m) {
            float iv = iou_g(s_gtb4[m], bp.x, bp.y, bp.z, bp.w, area_b);
            if (iv > best) { best = iv; bidx = m; }
        }
        const bool fg = best >= 0.5f;
        const float pri = rand_pri[(size_t)b * K_TOT + k];
        const uint32_t pb = __float_as_uint(pri);
        s_keys[k] = (fg ? (1ull << 50) : 0ull)
                  | ((uint64_t)pb << 20)
                  | ((uint64_t)k  << 7)
                  | (uint64_t)bidx;
        int bucket = min(255, (int)(pri * 256.0f));
        atomicAdd(&s_hist[fg ? 0 : 1][bucket], 1);
    }
    __syncthreads();

    for (int d = 1; d < 256; d <<= 1) {
        int v = 0, g = tid >> 8, t = tid & 255;
        bool act = (tid < 512) && (t + d < 256);
        if (act) v = s_hist[g][t + d];
        __syncthreads();
        if (act) s_hist[g][t] += v;
        __syncthreads();
    }

    if (tid == 0) {
        int fg_total = s_hist[0][0];
        int bg_total = s_hist[1][0];
        int nfg = min(NUM_FG_TGT, fg_total);
        int nbg = min(BATCH_PER - nfg, bg_total);
        s_needed[0] = nfg; s_needed[1] = nbg;
    }
    __syncthreads();

    if (tid < 512) {
        int g = tid >> 8, t = tid & 255;
        int need = s_needed[g];
        int St  = s_hist[g][t];
        int St1 = (t == 255) ? -1 : s_hist[g][t + 1];
        if (St >= need && St1 < need) s_T[g] = t;
    }
    if (tid < BATCH_PER) {
        s_out[0][tid] = 0.0f; s_out[1][tid] = -1.0f;
        s_out[2][tid] = -1.0f; s_out[3][tid] = -1.0f;
    }
    __syncthreads();

    const int nfg = s_needed[0], nbg = s_needed[1];
    if (tid < BATCH_PER)
        s_out[4][tid] = (tid < nfg + nbg) ? 1.0f : 0.0f;

    for (int k = tid; k < K_TOT; k += NTF) {
        uint64_t key = s_keys[k];
        int g = ((key >> 50) & 1ull) ? 0 : 1;
        uint32_t pbits = (uint32_t)((key >> 20) & 0x3FFFFFFFull);
        int bucket = min(255, (int)(__uint_as_float(pbits) * 256.0f));
        if (bucket >= s_T[g]) {
            int pos = atomicAdd(&s_cnt[g], 1);
            if (pos < HALF_CAP) s_cand[g * HALF_CAP + pos] = key;
        }
    }
    __syncthreads();

    const int fgc = min(s_cnt[0], HALF_CAP);
    const int bgc = min(s_cnt[1], HALF_CAP);
    for (int c = tid; c < fgc + bgc; c += NTF) {
        const bool isfg = (c < fgc);
        const int  base = isfg ? 0 : HALF_CAP;
        const int  cnt  = isfg ? fgc : bgc;
        const int  ci   = isfg ? c : (c - fgc);
        const uint64_t kc = s_cand[base + ci];
        int r = 0;
        for (int j = 0; j < cnt; ++j)
            r += (s_cand[base + j] > kc) ? 1 : 0;
        int slot = -1;
        if (isfg) { if (r < nfg) slot = r; }
        else      { if (r < nbg) slot = nfg + r; }
        if (slot >= 0) {
            int idx = (int)((kc >> 7) & 0x1FFFull);
            int mi  = (int)(kc & 0x7Full);
            float4 bp;
            if (idx < N_PROP)
                bp = *(const float4*)(prop_boxes + ((size_t)b * N_PROP + idx) * 4);
            else
                bp = s_gtb4[idx - N_PROP];
            const float area_b = box_area(bp);
            float iou = iou_g(s_gtb4[mi], bp.x, bp.y, bp.z, bp.w, area_b);
            s_out[0][slot] = iou;
            s_out[1][slot] = (float)idx;
            s_out[2][slot] = (float)(isfg ? s_gtc[mi] : NUM_CLASSES_);
            s_out[3][slot] = (float)mi;
        }
    }
    __syncthreads();

    for (int i = tid; i < 5 * BATCH_PER; i += NTF) {
        int o = i / BATCH_PER, p = i % BATCH_PER;
        out[(size_t)o * OUT_STRIDE + (size_t)b * BATCH_PER + p] = s_out[o][p];
    }
}

extern "C" void kernel_launch(void* const* d_in, const int* in_sizes, int n_in,
                              void* d_out, int out_size, void* d_ws, size_t ws_size,
                              hipStream_t stream) {
    const float* gt_boxes   = (const float*)d_in[0];  // [64,100,4]
    const float* prop_boxes = (const float*)d_in[1];  // [64,4000,4]
    const int*   gt_classes = (const int*)  d_in[2];  // [64,100]
    const float* rand_pri   = (const float*)d_in[3];  // [64,4100]
    float* out = (float*)d_out;                       // 5 x [64,512] float32, concat

    const size_t need_ws = (size_t)B_IMG * K_TOT * sizeof(uint64_t);  // 2.1 MB
    if (d_ws != nullptr && ws_size >= need_ws) {
        uint64_t* keys = (uint64_t*)d_ws;
        match_kernel<<<B_IMG * BPI1, NT1, 0, stream>>>(gt_boxes, prop_boxes,
                                                       rand_pri, keys);
        select_kernel<<<B_IMG, NTH, 0, stream>>>(gt_boxes, prop_boxes,
                                                 gt_classes, keys, out);
    } else {
        roiheads_fallback<<<B_IMG, NTF, 0, stream>>>(gt_boxes, prop_boxes,
                                                     gt_classes, rand_pri, out);
    }
}